// Round 8
// baseline (3222.834 us; speedup 1.0000x reference)
//
#include <hip/hip_runtime.h>
#include <hip/hip_bf16.h>

// FFJORD: 3 bijectors x 8 DOPRI5 steps (FSAL -> 144 MLP evals total).
// MLP: [z(4), cond(4), t(1)] ->128 ->128 ->4, tanh,tanh,linear.
//
// R8 = R7 (passed, 3.20ms: phi-trick, zero-shuffle, W2-via-LDS staging,
//      LDS ks, pair-Pade tanh) + ONE change:
//  - tanh Pade core forced to packed-f32 VOP3P (v_pk_mul/add/fma_f32) via
//    inline asm: 6 pk-ops per PAIR instead of ~13 scalar ops. Same rational
//    function x(x^4+105x^2+945) / (15(x^4+28x^2+63)), clamp +-3.4, one
//    v_rcp per pair with the 1/15 folded into the reciprocal.
//    (R7 cycle model: ~2200 VALU cyc/eval, tanh ~1200 -> ~750.)
//
// Phi-trick recap: k-index permutation phi chosen so each lane's L2/L3
// B-frag is the concatenation of its own cvt_pk'd C-frag words -> inter-layer
// transpose costs zero instructions/LDS/barriers (A/B staging share the map).

#define NBIJ 3
#define NSTEP 8

typedef float f32x4 __attribute__((ext_vector_type(4)));
typedef float f32x2 __attribute__((ext_vector_type(2)));
typedef short short8 __attribute__((ext_vector_type(8)));
typedef unsigned u32x4 __attribute__((ext_vector_type(4)));

union U4S8 { u32x4 u; short8 s; };

__device__ static const float AC[7][6] = {
    {0.f, 0.f, 0.f, 0.f, 0.f, 0.f},
    {0.2f, 0.f, 0.f, 0.f, 0.f, 0.f},
    {0.075f, 0.225f, 0.f, 0.f, 0.f, 0.f},
    {(float)(44.0/45.0), (float)(-56.0/15.0), (float)(32.0/9.0), 0.f, 0.f, 0.f},
    {(float)(19372.0/6561.0), (float)(-25360.0/2187.0), (float)(64448.0/6561.0),
     (float)(-212.0/729.0), 0.f, 0.f},
    {(float)(9017.0/3168.0), (float)(-355.0/33.0), (float)(46732.0/5247.0),
     (float)(49.0/176.0), (float)(-5103.0/18656.0), 0.f},
    {(float)(35.0/384.0), 0.0f, (float)(500.0/1113.0), (float)(125.0/192.0),
     (float)(-2187.0/6784.0), (float)(11.0/84.0)},
};
__device__ static const float CN[7] = {
    0.0f, 0.2f, 0.3f, 0.8f, (float)(8.0/9.0), 1.0f, 1.0f
};

__device__ __forceinline__ unsigned short bf16_bits(float a) {
    union { __hip_bfloat16 h; unsigned short u; } v;
    v.h = __float2bfloat16(a);   // RNE (staging only)
    return v.u;
}
__device__ __forceinline__ unsigned pk_manual(float a, float b) {
    return (unsigned)bf16_bits(a) | ((unsigned)bf16_bits(b) << 16);
}
__device__ __forceinline__ unsigned cvt_pk(float lo, float hi) {
    unsigned r;
    asm("v_cvt_pk_bf16_f32 %0, %1, %2" : "=v"(r) : "v"(lo), "v"(hi));
    return r;   // lo -> [15:0], hi -> [31:16]
}

// Pade numerator/denominator on a packed pair, forced VOP3P (full-rate
// 2-wide f32): num = x(x^4+105x^2+945), den = x^4+28x^2+63  (true den/15).
__device__ __forceinline__ f32x2 pade_nd(f32x2 x, f32x2 k105, f32x2 k945,
                                         f32x2 k28, f32x2 k63, f32x2* den) {
    f32x2 x2, num, d;
    asm("v_pk_mul_f32 %0, %3, %3\n\t"          // x2  = x*x
        "v_pk_add_f32 %1, %0, %4\n\t"           // num = x2 + 105
        "v_pk_fma_f32 %1, %0, %1, %5\n\t"       // num = x2*num + 945
        "v_pk_mul_f32 %1, %3, %1\n\t"           // num = x*num
        "v_pk_add_f32 %2, %0, %6\n\t"           // d   = x2 + 28
        "v_pk_fma_f32 %2, %0, %2, %7\n\t"       // d   = x2*d + 63
        : "=&v"(x2), "=&v"(num), "=&v"(d)
        : "v"(x), "v"(k105), "v"(k945), "v"(k28), "v"(k63));
    *den = d;
    return num;
}

// tanh on two values -> one packed bf16 word. Clamp +-3.4; one v_rcp for
// both denominators; 1/15 folded into the reciprocal.
__device__ __forceinline__ unsigned tanh2_pk(float a, float b,
    f32x2 k105, f32x2 k945, f32x2 k28, f32x2 k63) {
    f32x2 x = { __builtin_amdgcn_fmed3f(a, -3.4f, 3.4f),
                __builtin_amdgcn_fmed3f(b, -3.4f, 3.4f) };
    f32x2 d;
    f32x2 num = pade_nd(x, k105, k945, k28, k63, &d);
    float rr = __builtin_amdgcn_rcpf(d[0] * d[1]) * (1.0f / 15.0f);
    float r0 = rr * d[1], r1 = rr * d[0];
    return cvt_pk(num[0] * r0, num[1] * r1);
}

struct SMem {
    alignas(16) short w1f[8][64][8];      // W1^T A-frags (k=g*8+e map)   8 KB
    alignas(16) short w3f[4][64][8];      // W3^T A-frags (phi map)       4 KB
    alignas(16) unsigned w2s[32][64][4];  // W2^T A-frag stage           32 KB
    alignas(16) float b1[128];
    alignas(16) float b2[128];
    alignas(16) float b3[16];             // zero-padded past 4
    alignas(16) f32x4 ks[4][7][16];       // [wid][stage][r]              7 KB
};

__device__ __forceinline__ f32x4 mlp_eval(
    const f32x4 y, float t, unsigned c01, unsigned c23,
    const u32x4 (&w2r)[8][4], const SMem* sm, int wid, int lane,
    f32x2 k105, f32x2 k945, f32x2 k28, f32x2 k63)
{
    const int g = lane >> 4;

    // ---- input B-frag (k = g*8+e): g0 = [z0..z3,c0..c3], g1 = [t,0,...]
    U4S8 inf;
    {
        unsigned zp01 = cvt_pk(y[0], y[1]);
        unsigned zp23 = cvt_pk(y[2], y[3]);
        unsigned tp   = cvt_pk(t, 0.0f);
        inf.u[0] = (g == 0) ? zp01 : ((g == 1) ? tp : 0u);
        inf.u[1] = (g == 0) ? zp23 : 0u;
        inf.u[2] = (g == 0) ? c01  : 0u;
        inf.u[3] = (g == 0) ? c23  : 0u;
    }

    const f32x4* b1p = (const f32x4*)&sm->b1[g * 4];   // +jt*4 -> imm offset
    const f32x4* b2p = (const f32x4*)&sm->b2[g * 4];
    const short8* w1p = (const short8*)&sm->w1f[0][lane][0];  // +jt*64
    const short8* w3p = (const short8*)&sm->w3f[0][lane][0];  // +kt*64

    // ---- L1: 8 MFMA; tanh+pack straight into L2 B-frags (phi layout)
    u32x4 hf[4];
    #pragma unroll
    for (int jt = 0; jt < 8; ++jt) {
        U4S8 a; a.s = w1p[jt * 64];
        f32x4 c = b1p[jt * 4];
        c = __builtin_amdgcn_mfma_f32_16x16x32_bf16(a.s, inf.s, c, 0, 0, 0);
        hf[jt >> 1][(jt & 1) * 2 + 0] = tanh2_pk(c[0], c[1], k105, k945, k28, k63);
        hf[jt >> 1][(jt & 1) * 2 + 1] = tanh2_pk(c[2], c[3], k105, k945, k28, k63);
    }

    // ---- L2: 32 MFMA (A in regs), tanh+pack into L3 B-frags (phi layout)
    u32x4 hf2[4];
    #pragma unroll
    for (int jt = 0; jt < 8; ++jt) {
        f32x4 c = b2p[jt * 4];
        #pragma unroll
        for (int kt = 0; kt < 4; ++kt) {
            U4S8 w; w.u = w2r[jt][kt];
            U4S8 bb; bb.u = hf[kt];
            c = __builtin_amdgcn_mfma_f32_16x16x32_bf16(w.s, bb.s, c, 0, 0, 0);
        }
        hf2[jt >> 1][(jt & 1) * 2 + 0] = tanh2_pk(c[0], c[1], k105, k945, k28, k63);
        hf2[jt >> 1][(jt & 1) * 2 + 1] = tanh2_pk(c[2], c[3], k105, k945, k28, k63);
    }

    // ---- L3: 4 MFMA
    f32x4 c3 = *(const f32x4*)&sm->b3[g * 4];
    #pragma unroll
    for (int kt = 0; kt < 4; ++kt) {
        U4S8 a; a.s = w3p[kt * 64];
        U4S8 bb; bb.u = hf2[kt];
        c3 = __builtin_amdgcn_mfma_f32_16x16x32_bf16(a.s, bb.s, c3, 0, 0, 0);
    }
    return c3;   // rows: feature d = g*4+reg (valid g0, d<4); col = batch r
}

extern "C" __global__ void __launch_bounds__(256, 2) ffjord_kernel(
    const float* __restrict__ X, const float* __restrict__ CIN,
    const float* __restrict__ W1, const float* __restrict__ B1,
    const float* __restrict__ W2, const float* __restrict__ B2,
    const float* __restrict__ W3, const float* __restrict__ B3,
    float* __restrict__ OUT)
{
    __shared__ SMem sm;
    const int tid = threadIdx.x;
    const int wid = tid >> 6, lane = tid & 63;
    const int r = lane & 15, g = lane >> 4;
    const int rowbase = blockIdx.x * 64 + wid * 16;
    const float dt = 0.125f;

    const f32x2 k105 = {105.0f, 105.0f};
    const f32x2 k945 = {945.0f, 945.0f};
    const f32x2 k28  = {28.0f, 28.0f};
    const f32x2 k63  = {63.0f, 63.0f};

    f32x4 z = {0.f, 0.f, 0.f, 0.f};
    unsigned c01 = 0u, c23 = 0u;
    if (g == 0) {
        float4 xv = reinterpret_cast<const float4*>(X)[rowbase + r];
        z[0] = xv.x; z[1] = xv.y; z[2] = xv.z; z[3] = xv.w;
        float4 cv = reinterpret_cast<const float4*>(CIN)[rowbase + r];
        c01 = pk_manual(cv.x, cv.y); c23 = pk_manual(cv.z, cv.w);
    }

    u32x4 w2r[8][4];

    for (int bij = 0; bij < NBIJ; ++bij) {
        __syncthreads();   // prior-bijector LDS reads done before restaging

        // ---- stage W1^T A-frags (k = g*8+e; rows k>=9 zero)
        for (int e2 = tid; e2 < 512; e2 += 256) {
            int jt = e2 >> 6, ln = e2 & 63, g2 = ln >> 4, r2 = ln & 15;
            int j = jt * 16 + r2;
            unsigned uu[4];
            #pragma unroll
            for (int ep = 0; ep < 4; ++ep) {
                int k0 = g2 * 8 + 2 * ep;
                float a = (k0 < 9)     ? W1[(bij * 9 + k0) * 128 + j]     : 0.f;
                float b = (k0 + 1 < 9) ? W1[(bij * 9 + k0 + 1) * 128 + j] : 0.f;
                uu[ep] = pk_manual(a, b);
            }
            *(uint4*)&sm.w1f[jt][ln][0] = make_uint4(uu[0], uu[1], uu[2], uu[3]);
        }
        // ---- stage W3^T A-frags with phi map: f0 = 32kt+16*(ep>>1)+4g+(ep&1)*2
        {
            int kt = tid >> 6, ln = tid & 63, g2 = ln >> 4, d = ln & 15;
            unsigned uu[4];
            #pragma unroll
            for (int ep = 0; ep < 4; ++ep) {
                int f0 = 32 * kt + 16 * (ep >> 1) + 4 * g2 + (ep & 1) * 2;
                float a = (d < 4) ? W3[(bij * 128 + f0) * 4 + d]     : 0.f;
                float b = (d < 4) ? W3[(bij * 128 + f0 + 1) * 4 + d] : 0.f;
                uu[ep] = pk_manual(a, b);
            }
            *(uint4*)&sm.w3f[kt][ln][0] = make_uint4(uu[0], uu[1], uu[2], uu[3]);
        }
        // ---- stage W2^T A-frags into LDS (phi map), low register pressure:
        // thread owns (kt, ln) and builds frags for all 8 jt (runtime loop).
        {
            int kt = tid >> 6, ln = tid & 63, g2 = ln >> 4, r2 = ln & 15;
            for (int jt = 0; jt < 8; ++jt) {
                unsigned uu[4];
                #pragma unroll
                for (int ep = 0; ep < 4; ++ep) {
                    int f0 = 32 * kt + 16 * (ep >> 1) + 4 * g2 + (ep & 1) * 2;
                    int j = jt * 16 + r2;
                    uu[ep] = pk_manual(W2[(bij * 128 + f0) * 128 + j],
                                       W2[(bij * 128 + f0 + 1) * 128 + j]);
                }
                *(uint4*)&sm.w2s[jt * 4 + kt][ln][0] =
                    make_uint4(uu[0], uu[1], uu[2], uu[3]);
            }
        }
        if (tid < 128) { sm.b1[tid] = B1[bij * 128 + tid];
                         sm.b2[tid] = B2[bij * 128 + tid]; }
        if (tid < 16)  sm.b3[tid] = (tid < 4) ? B3[bij * 4 + tid] : 0.f;
        __syncthreads();

        // ---- per-wave: W2 frags LDS -> persistent regs (32x ds_read_b128)
        #pragma unroll
        for (int jt = 0; jt < 8; ++jt)
            #pragma unroll
            for (int kt = 0; kt < 4; ++kt)
                w2r[jt][kt] = *(const u32x4*)&sm.w2s[jt * 4 + kt][lane][0];

        // ---- initial k1 = f(0, z)
        f32x4 kf = mlp_eval(z, 0.0f, c01, c23, w2r, &sm, wid, lane,
                            k105, k945, k28, k63);
        if (g == 0) sm.ks[wid][0][r] = kf;

        for (int s = 0; s < NSTEP; ++s) {
            float t0 = s * dt;
            bool last = (s == NSTEP - 1);
            for (int st = 1; st <= 6; ++st) {
                f32x4 y = z;
                for (int j = 0; j < st; ++j) {
                    float a = dt * AC[st][j];
                    f32x4 kj = sm.ks[wid][j][r];
                    y += a * kj;
                }
                if (st == 6) { z = y; if (last) break; }  // FSAL: y IS z_next
                float tt = fmaf(CN[st], dt, t0);
                f32x4 kn = mlp_eval(y, tt, c01, c23, w2r, &sm, wid, lane,
                                    k105, k945, k28, k63);
                int di = (st == 6) ? 0 : st;              // FSAL: k7 -> next k1
                if (g == 0) sm.ks[wid][di][r] = kn;
            }
        }
    }

    if (g == 0) {
        float4 o; o.x = z[0]; o.y = z[1]; o.z = z[2]; o.w = z[3];
        reinterpret_cast<float4*>(OUT)[rowbase + r] = o;
    }
}

extern "C" void kernel_launch(void* const* d_in, const int* in_sizes, int n_in,
                              void* d_out, int out_size, void* d_ws, size_t ws_size,
                              hipStream_t stream) {
    const float* X  = (const float*)d_in[0];
    const float* CI = (const float*)d_in[1];
    const float* W1 = (const float*)d_in[2];
    const float* B1 = (const float*)d_in[3];
    const float* W2 = (const float*)d_in[4];
    const float* B2 = (const float*)d_in[5];
    const float* W3 = (const float*)d_in[6];
    const float* B3 = (const float*)d_in[7];
    float* OUT = (float*)d_out;

    int btot = in_sizes[0] / 4;          // 262144 rows
    int grid = btot / 64;                // 64 rows per block (4 waves x 16)
    ffjord_kernel<<<grid, 256, 0, stream>>>(X, CI, W1, B1, W2, B2, W3, B3, OUT);
}

// Round 9
// 2734.349 us; speedup vs baseline: 1.1786x; 1.1786x over previous
//
#include <hip/hip_runtime.h>
#include <hip/hip_bf16.h>

// FFJORD: 3 bijectors x 8 DOPRI5 steps (FSAL -> 144 MLP evals total).
// MLP: [z(4), cond(4), t(1)] ->128 ->128 ->4, tanh,tanh,linear.
//
// R9 = R7 core (phi-trick, zero-shuffle, W2-via-LDS staging, LDS ks)
//      + ONE change: tanh via 4096-entry nearest-neighbor LDS LUT.
//   R8 lesson: v_pk_*_f32 is 64b/lane on a 32-wide SIMD (4 cyc vs 2) -> no
//   throughput win; tanh ARITHMETIC (~40 cyc/pair measured) is the wall.
//   LUT: idx = trunc(min(fma(x,512,2048.5), 4095)) (cvt_u32 saturates
//   negatives to 0), ds_read_u16 yields the bf16 tanh bits directly,
//   lshl_or packs the pair: ~9 VALU ops/pair, gathers ride the idle LDS pipe.
//   Error: step 1/512 -> <=1e-3/value (~bf16 quantum); clamp at +-4 adds
//   6.7e-4 tail error. Table filled once per block (tanhf, cold path).
//
// Phi-trick recap: k-index permutation phi chosen so each lane's L2/L3
// B-frag is the concatenation of its own cvt_pk'd C-frag words -> inter-layer
// transpose costs zero instructions/LDS/barriers (A/B staging share the map).

#define NBIJ 3
#define NSTEP 8

typedef float f32x4 __attribute__((ext_vector_type(4)));
typedef short short8 __attribute__((ext_vector_type(8)));
typedef unsigned u32x4 __attribute__((ext_vector_type(4)));

union U4S8 { u32x4 u; short8 s; };

__device__ static const float AC[7][6] = {
    {0.f, 0.f, 0.f, 0.f, 0.f, 0.f},
    {0.2f, 0.f, 0.f, 0.f, 0.f, 0.f},
    {0.075f, 0.225f, 0.f, 0.f, 0.f, 0.f},
    {(float)(44.0/45.0), (float)(-56.0/15.0), (float)(32.0/9.0), 0.f, 0.f, 0.f},
    {(float)(19372.0/6561.0), (float)(-25360.0/2187.0), (float)(64448.0/6561.0),
     (float)(-212.0/729.0), 0.f, 0.f},
    {(float)(9017.0/3168.0), (float)(-355.0/33.0), (float)(46732.0/5247.0),
     (float)(49.0/176.0), (float)(-5103.0/18656.0), 0.f},
    {(float)(35.0/384.0), 0.0f, (float)(500.0/1113.0), (float)(125.0/192.0),
     (float)(-2187.0/6784.0), (float)(11.0/84.0)},
};
__device__ static const float CN[7] = {
    0.0f, 0.2f, 0.3f, 0.8f, (float)(8.0/9.0), 1.0f, 1.0f
};

__device__ __forceinline__ unsigned short bf16_bits(float a) {
    union { __hip_bfloat16 h; unsigned short u; } v;
    v.h = __float2bfloat16(a);   // RNE (staging / table fill only)
    return v.u;
}
__device__ __forceinline__ unsigned pk_manual(float a, float b) {
    return (unsigned)bf16_bits(a) | ((unsigned)bf16_bits(b) << 16);
}
__device__ __forceinline__ unsigned cvt_pk(float lo, float hi) {
    unsigned r;
    asm("v_cvt_pk_bf16_f32 %0, %1, %2" : "=v"(r) : "v"(lo), "v"(hi));
    return r;   // lo -> [15:0], hi -> [31:16]
}

struct SMem {
    alignas(16) short w1f[8][64][8];      // W1^T A-frags (k=g*8+e map)   8 KB
    alignas(16) short w3f[4][64][8];      // W3^T A-frags (phi map)       4 KB
    alignas(16) unsigned w2s[32][64][4];  // W2^T A-frag stage           32 KB
    alignas(16) float b1[128];
    alignas(16) float b2[128];
    alignas(16) float b3[16];             // zero-padded past 4
    alignas(16) f32x4 ks[4][7][16];       // [wid][stage][r]              7 KB
    alignas(16) unsigned short ttab[4096];// tanh LUT, x-step 1/512       8 KB
};

// tanh on two values -> one packed bf16 word, via nearest-neighbor LUT.
__device__ __forceinline__ unsigned tanh2_lut(float a, float b,
                                              const unsigned short* tab) {
    float pa = fminf(fmaf(a, 512.0f, 2048.5f), 4095.0f);
    float pb = fminf(fmaf(b, 512.0f, 2048.5f), 4095.0f);
    unsigned ia = (unsigned)pa;   // v_cvt_u32_f32: negative saturates to 0
    unsigned ib = (unsigned)pb;
    unsigned lo = tab[ia];        // ds_read_u16 (zero-extended)
    unsigned hi = tab[ib];
    return lo | (hi << 16);       // v_lshl_or_b32
}

__device__ __forceinline__ f32x4 mlp_eval(
    const f32x4 y, float t, unsigned c01, unsigned c23,
    const u32x4 (&w2r)[8][4], const SMem* sm, int wid, int lane)
{
    const int g = lane >> 4;
    const unsigned short* tab = &sm->ttab[0];

    // ---- input B-frag (k = g*8+e): g0 = [z0..z3,c0..c3], g1 = [t,0,...]
    U4S8 inf;
    {
        unsigned zp01 = cvt_pk(y[0], y[1]);
        unsigned zp23 = cvt_pk(y[2], y[3]);
        unsigned tp   = cvt_pk(t, 0.0f);
        inf.u[0] = (g == 0) ? zp01 : ((g == 1) ? tp : 0u);
        inf.u[1] = (g == 0) ? zp23 : 0u;
        inf.u[2] = (g == 0) ? c01  : 0u;
        inf.u[3] = (g == 0) ? c23  : 0u;
    }

    const f32x4* b1p = (const f32x4*)&sm->b1[g * 4];   // +jt*4 -> imm offset
    const f32x4* b2p = (const f32x4*)&sm->b2[g * 4];
    const short8* w1p = (const short8*)&sm->w1f[0][lane][0];  // +jt*64
    const short8* w3p = (const short8*)&sm->w3f[0][lane][0];  // +kt*64

    // ---- L1: 8 MFMA; tanh-LUT+pack straight into L2 B-frags (phi layout)
    u32x4 hf[4];
    #pragma unroll
    for (int jt = 0; jt < 8; ++jt) {
        U4S8 a; a.s = w1p[jt * 64];
        f32x4 c = b1p[jt * 4];
        c = __builtin_amdgcn_mfma_f32_16x16x32_bf16(a.s, inf.s, c, 0, 0, 0);
        hf[jt >> 1][(jt & 1) * 2 + 0] = tanh2_lut(c[0], c[1], tab);
        hf[jt >> 1][(jt & 1) * 2 + 1] = tanh2_lut(c[2], c[3], tab);
    }

    // ---- L2: 32 MFMA (A in regs), tanh-LUT+pack into L3 B-frags (phi layout)
    u32x4 hf2[4];
    #pragma unroll
    for (int jt = 0; jt < 8; ++jt) {
        f32x4 c = b2p[jt * 4];
        #pragma unroll
        for (int kt = 0; kt < 4; ++kt) {
            U4S8 w; w.u = w2r[jt][kt];
            U4S8 bb; bb.u = hf[kt];
            c = __builtin_amdgcn_mfma_f32_16x16x32_bf16(w.s, bb.s, c, 0, 0, 0);
        }
        hf2[jt >> 1][(jt & 1) * 2 + 0] = tanh2_lut(c[0], c[1], tab);
        hf2[jt >> 1][(jt & 1) * 2 + 1] = tanh2_lut(c[2], c[3], tab);
    }

    // ---- L3: 4 MFMA
    f32x4 c3 = *(const f32x4*)&sm->b3[g * 4];
    #pragma unroll
    for (int kt = 0; kt < 4; ++kt) {
        U4S8 a; a.s = w3p[kt * 64];
        U4S8 bb; bb.u = hf2[kt];
        c3 = __builtin_amdgcn_mfma_f32_16x16x32_bf16(a.s, bb.s, c3, 0, 0, 0);
    }
    return c3;   // rows: feature d = g*4+reg (valid g0, d<4); col = batch r
}

extern "C" __global__ void __launch_bounds__(256, 2) ffjord_kernel(
    const float* __restrict__ X, const float* __restrict__ CIN,
    const float* __restrict__ W1, const float* __restrict__ B1,
    const float* __restrict__ W2, const float* __restrict__ B2,
    const float* __restrict__ W3, const float* __restrict__ B3,
    float* __restrict__ OUT)
{
    __shared__ SMem sm;
    const int tid = threadIdx.x;
    const int wid = tid >> 6, lane = tid & 63;
    const int r = lane & 15, g = lane >> 4;
    const int rowbase = blockIdx.x * 64 + wid * 16;
    const float dt = 0.125f;

    // ---- fill tanh LUT (once per block; ordered by the loop-top barrier)
    for (int i = tid; i < 4096; i += 256) {
        float xv = (i - 2048) * (1.0f / 512.0f);
        sm.ttab[i] = bf16_bits(tanhf(xv));
    }

    f32x4 z = {0.f, 0.f, 0.f, 0.f};
    unsigned c01 = 0u, c23 = 0u;
    if (g == 0) {
        float4 xv = reinterpret_cast<const float4*>(X)[rowbase + r];
        z[0] = xv.x; z[1] = xv.y; z[2] = xv.z; z[3] = xv.w;
        float4 cv = reinterpret_cast<const float4*>(CIN)[rowbase + r];
        c01 = pk_manual(cv.x, cv.y); c23 = pk_manual(cv.z, cv.w);
    }

    u32x4 w2r[8][4];

    for (int bij = 0; bij < NBIJ; ++bij) {
        __syncthreads();   // prior LDS reads (and table fill) done before staging

        // ---- stage W1^T A-frags (k = g*8+e; rows k>=9 zero)
        for (int e2 = tid; e2 < 512; e2 += 256) {
            int jt = e2 >> 6, ln = e2 & 63, g2 = ln >> 4, r2 = ln & 15;
            int j = jt * 16 + r2;
            unsigned uu[4];
            #pragma unroll
            for (int ep = 0; ep < 4; ++ep) {
                int k0 = g2 * 8 + 2 * ep;
                float a = (k0 < 9)     ? W1[(bij * 9 + k0) * 128 + j]     : 0.f;
                float b = (k0 + 1 < 9) ? W1[(bij * 9 + k0 + 1) * 128 + j] : 0.f;
                uu[ep] = pk_manual(a, b);
            }
            *(uint4*)&sm.w1f[jt][ln][0] = make_uint4(uu[0], uu[1], uu[2], uu[3]);
        }
        // ---- stage W3^T A-frags with phi map: f0 = 32kt+16*(ep>>1)+4g+(ep&1)*2
        {
            int kt = tid >> 6, ln = tid & 63, g2 = ln >> 4, d = ln & 15;
            unsigned uu[4];
            #pragma unroll
            for (int ep = 0; ep < 4; ++ep) {
                int f0 = 32 * kt + 16 * (ep >> 1) + 4 * g2 + (ep & 1) * 2;
                float a = (d < 4) ? W3[(bij * 128 + f0) * 4 + d]     : 0.f;
                float b = (d < 4) ? W3[(bij * 128 + f0 + 1) * 4 + d] : 0.f;
                uu[ep] = pk_manual(a, b);
            }
            *(uint4*)&sm.w3f[kt][ln][0] = make_uint4(uu[0], uu[1], uu[2], uu[3]);
        }
        // ---- stage W2^T A-frags into LDS (phi map), low register pressure:
        // thread owns (kt, ln) and builds frags for all 8 jt (runtime loop).
        {
            int kt = tid >> 6, ln = tid & 63, g2 = ln >> 4, r2 = ln & 15;
            for (int jt = 0; jt < 8; ++jt) {
                unsigned uu[4];
                #pragma unroll
                for (int ep = 0; ep < 4; ++ep) {
                    int f0 = 32 * kt + 16 * (ep >> 1) + 4 * g2 + (ep & 1) * 2;
                    int j = jt * 16 + r2;
                    uu[ep] = pk_manual(W2[(bij * 128 + f0) * 128 + j],
                                       W2[(bij * 128 + f0 + 1) * 128 + j]);
                }
                *(uint4*)&sm.w2s[jt * 4 + kt][ln][0] =
                    make_uint4(uu[0], uu[1], uu[2], uu[3]);
            }
        }
        if (tid < 128) { sm.b1[tid] = B1[bij * 128 + tid];
                         sm.b2[tid] = B2[bij * 128 + tid]; }
        if (tid < 16)  sm.b3[tid] = (tid < 4) ? B3[bij * 4 + tid] : 0.f;
        __syncthreads();

        // ---- per-wave: W2 frags LDS -> persistent regs (32x ds_read_b128)
        #pragma unroll
        for (int jt = 0; jt < 8; ++jt)
            #pragma unroll
            for (int kt = 0; kt < 4; ++kt)
                w2r[jt][kt] = *(const u32x4*)&sm.w2s[jt * 4 + kt][lane][0];

        // ---- initial k1 = f(0, z)
        f32x4 kf = mlp_eval(z, 0.0f, c01, c23, w2r, &sm, wid, lane);
        if (g == 0) sm.ks[wid][0][r] = kf;

        for (int s = 0; s < NSTEP; ++s) {
            float t0 = s * dt;
            bool last = (s == NSTEP - 1);
            for (int st = 1; st <= 6; ++st) {
                f32x4 y = z;
                for (int j = 0; j < st; ++j) {
                    float a = dt * AC[st][j];
                    f32x4 kj = sm.ks[wid][j][r];
                    y += a * kj;
                }
                if (st == 6) { z = y; if (last) break; }  // FSAL: y IS z_next
                float tt = fmaf(CN[st], dt, t0);
                f32x4 kn = mlp_eval(y, tt, c01, c23, w2r, &sm, wid, lane);
                int di = (st == 6) ? 0 : st;              // FSAL: k7 -> next k1
                if (g == 0) sm.ks[wid][di][r] = kn;
            }
        }
    }

    if (g == 0) {
        float4 o; o.x = z[0]; o.y = z[1]; o.z = z[2]; o.w = z[3];
        reinterpret_cast<float4*>(OUT)[rowbase + r] = o;
    }
}

extern "C" void kernel_launch(void* const* d_in, const int* in_sizes, int n_in,
                              void* d_out, int out_size, void* d_ws, size_t ws_size,
                              hipStream_t stream) {
    const float* X  = (const float*)d_in[0];
    const float* CI = (const float*)d_in[1];
    const float* W1 = (const float*)d_in[2];
    const float* B1 = (const float*)d_in[3];
    const float* W2 = (const float*)d_in[4];
    const float* B2 = (const float*)d_in[5];
    const float* W3 = (const float*)d_in[6];
    const float* B3 = (const float*)d_in[7];
    float* OUT = (float*)d_out;

    int btot = in_sizes[0] / 4;          // 262144 rows
    int grid = btot / 64;                // 64 rows per block (4 waves x 16)
    ffjord_kernel<<<grid, 256, 0, stream>>>(X, CI, W1, B1, W2, B2, W3, B3, OUT);
}